// Round 2
// baseline (402.266 us; speedup 1.0000x reference)
//
#include <hip/hip_runtime.h>
#include <math.h>

#define B_ 8
#define K_ 100000
#define NANN 32
#define C_ 80
#define BLOCK 256
#define CHUNK 256           // anchors per block
#define ST_NEG 200
#define ST_IGN 255

__global__ void zero_ws_kernel(float* ws) {
    int i = threadIdx.x;
    if (i < 3 * B_) ws[i] = 0.0f;
}

__launch_bounds__(BLOCK)
__global__ void focal_main(const float* __restrict__ cls,
                           const float* __restrict__ reg,
                           const float* __restrict__ anc,
                           const float* __restrict__ ann,
                           float* __restrict__ ws) {
    const int b     = blockIdx.y;
    const int chunk = blockIdx.x;
    const int tid   = threadIdx.x;

    __shared__ float s_ann[NANN * 5];
    __shared__ unsigned char s_state[CHUNK];
    __shared__ float s_red[(BLOCK / 64) * 3];

    if (tid < NANN * 5) s_ann[tid] = ann[b * NANN * 5 + tid];
    __syncthreads();

    const int k0 = chunk * CHUNK;
    const int k  = k0 + tid;

    float reg_acc = 0.0f;
    float np_acc  = 0.0f;
    unsigned char st = ST_IGN;

    if (k < K_) {
        float4 a = *(const float4*)(anc + (size_t)k * 4);
        float aw = a.z - a.x, ah = a.w - a.y;
        float area_a = aw * ah;

        float best = -2.0f;
        int bestj = 0;
        for (int j = 0; j < NANN; ++j) {
            float bx1 = s_ann[j * 5 + 0], by1 = s_ann[j * 5 + 1];
            float bx2 = s_ann[j * 5 + 2], by2 = s_ann[j * 5 + 3];
            float lbl = s_ann[j * 5 + 4];
            float area_b = (bx2 - bx1) * (by2 - by1);
            float iw = fmaxf(fminf(a.z, bx2) - fmaxf(a.x, bx1), 0.0f);
            float ih = fmaxf(fminf(a.w, by2) - fmaxf(a.y, by1), 0.0f);
            float inter = iw * ih;
            float uni = fmaxf(area_a + area_b - inter, 1e-8f);
            float iou = inter / uni;
            if (lbl < 0.0f) iou = -1.0f;   // invalid annotation mask
            if (iou > best) { best = iou; bestj = j; }  // first-max = jnp.argmax
        }

        if (best >= 0.5f) {
            st = (unsigned char)(int)s_ann[bestj * 5 + 4];
            np_acc = 1.0f;
            // regression smooth-L1 for this positive anchor
            float gx1 = s_ann[bestj * 5 + 0], gy1 = s_ann[bestj * 5 + 1];
            float gx2 = s_ann[bestj * 5 + 2], gy2 = s_ann[bestj * 5 + 3];
            float gw = fmaxf(gx2 - gx1, 1.0f);
            float gh = fmaxf(gy2 - gy1, 1.0f);
            float gcx = gx1 + 0.5f * gw, gcy = gy1 + 0.5f * gh;
            float acx = a.x + 0.5f * aw, acy = a.y + 0.5f * ah;
            float4 r = *(const float4*)(reg + ((size_t)b * K_ + k) * 4);
            float t0 = ((gcx - acx) / aw) / 0.1f;
            float t1 = ((gcy - acy) / ah) / 0.1f;
            float t2 = __logf(gw / aw) / 0.2f;
            float t3 = __logf(gh / ah) / 0.2f;
            float d, s;
            d = fabsf(t0 - r.x); s = (d <= 1.0f / 9.0f) ? 4.5f * d * d : d - 0.5f / 9.0f; reg_acc += s;
            d = fabsf(t1 - r.y); s = (d <= 1.0f / 9.0f) ? 4.5f * d * d : d - 0.5f / 9.0f; reg_acc += s;
            d = fabsf(t2 - r.z); s = (d <= 1.0f / 9.0f) ? 4.5f * d * d : d - 0.5f / 9.0f; reg_acc += s;
            d = fabsf(t3 - r.w); s = (d <= 1.0f / 9.0f) ? 4.5f * d * d : d - 0.5f / 9.0f; reg_acc += s;
        } else if (best < 0.4f) {
            st = ST_NEG;
        } else {
            st = ST_IGN;
        }
    }
    s_state[tid] = st;
    __syncthreads();

    // ---- classification sweep: contiguous slab [na anchors x 80 classes] ----
    const int na  = min(CHUNK, K_ - k0);
    const int nf4 = na * (C_ / 4);   // float4s in this slab (20 per anchor)
    const float4* cp = (const float4*)(cls + ((size_t)b * K_ + (size_t)k0) * C_);

    float cls_acc = 0.0f;
    for (int idx = tid; idx < nf4; idx += BLOCK) {
        int a_l = idx / (C_ / 4);
        int c4  = idx - a_l * (C_ / 4);
        unsigned char s = s_state[a_l];
        if (s != ST_IGN) {
            float4 x = cp[idx];
            int cbase = c4 * 4;
            float px[4] = {x.x, x.y, x.z, x.w};
#pragma unroll
            for (int e = 0; e < 4; ++e) {
                float p = fminf(fmaxf(px[e], 1e-4f), 1.0f - 1e-4f);
                bool ispos = ((int)s == cbase + e);
                float q  = ispos ? 1.0f - p : p;       // focal weight arg
                float lp = ispos ? p : 1.0f - p;       // bce arg
                float w  = (ispos ? 0.25f : 0.75f) * sqrtf(q);
                cls_acc += w * (-__logf(lp));
            }
        }
    }

    // ---- block reduction of (cls_acc, reg_acc, np_acc) ----
    float v0 = cls_acc, v1 = reg_acc, v2 = np_acc;
    for (int off = 32; off > 0; off >>= 1) {
        v0 += __shfl_down(v0, off, 64);
        v1 += __shfl_down(v1, off, 64);
        v2 += __shfl_down(v2, off, 64);
    }
    int wave = tid >> 6, lane = tid & 63;
    if (lane == 0) {
        s_red[wave * 3 + 0] = v0;
        s_red[wave * 3 + 1] = v1;
        s_red[wave * 3 + 2] = v2;
    }
    __syncthreads();
    if (tid == 0) {
        float c = 0.0f, rg = 0.0f, np = 0.0f;
        for (int w = 0; w < BLOCK / 64; ++w) {
            c  += s_red[w * 3 + 0];
            rg += s_red[w * 3 + 1];
            np += s_red[w * 3 + 2];
        }
        atomicAdd(&ws[b * 3 + 0], c);
        atomicAdd(&ws[b * 3 + 1], rg);
        atomicAdd(&ws[b * 3 + 2], np);
    }
}

__global__ void finalize_kernel(const float* __restrict__ ws, float* __restrict__ out) {
    if (threadIdx.x == 0) {
        float cs = 0.0f, rs = 0.0f;
        for (int b = 0; b < B_; ++b) {
            float c  = ws[b * 3 + 0];
            float r  = ws[b * 3 + 1];
            float np = ws[b * 3 + 2];
            cs += c / fmaxf(np, 1.0f);
            rs += (np > 0.0f) ? r / fmaxf(np * 4.0f, 1.0f) : 0.0f;
        }
        out[0] = cs / (float)B_;
        out[1] = rs / (float)B_;
    }
}

extern "C" void kernel_launch(void* const* d_in, const int* in_sizes, int n_in,
                              void* d_out, int out_size, void* d_ws, size_t ws_size,
                              hipStream_t stream) {
    const float* cls = (const float*)d_in[0];   // [B,K,C]
    const float* reg = (const float*)d_in[1];   // [B,K,4]
    const float* anc = (const float*)d_in[2];   // [1,K,4]
    const float* ann = (const float*)d_in[3];   // [B,NANN,5]
    float* out = (float*)d_out;                  // [2]
    float* ws  = (float*)d_ws;                   // 24 floats: per-batch {cls,reg,npos}

    zero_ws_kernel<<<1, 64, 0, stream>>>(ws);

    dim3 grid((K_ + CHUNK - 1) / CHUNK, B_);
    focal_main<<<grid, BLOCK, 0, stream>>>(cls, reg, anc, ann, ws);

    finalize_kernel<<<1, 64, 0, stream>>>(ws, out);
}

// Round 3
// 376.975 us; speedup vs baseline: 1.0671x; 1.0671x over previous
//
#include <hip/hip_runtime.h>
#include <math.h>

#define B_ 8
#define K_ 100000
#define NANN 32
#define C_ 80
#define BLOCK 256
#define CHUNK 256           // anchors per block
#define LN2 0.69314718056f

__global__ void zero_ws_kernel(float* ws) {
    int i = threadIdx.x;
    if (i < 3 * B_) ws[i] = 0.0f;
}

__device__ __forceinline__ float fast_log2(float x) {
#if __has_builtin(__builtin_amdgcn_logf)
    return __builtin_amdgcn_logf(x);      // raw v_log_f32 (log2)
#else
    return __log2f(x);
#endif
}
__device__ __forceinline__ float fast_sqrt(float x) {
#if __has_builtin(__builtin_amdgcn_sqrtf)
    return __builtin_amdgcn_sqrtf(x);     // raw v_sqrt_f32
#else
    return sqrtf(x);
#endif
}

__launch_bounds__(BLOCK)
__global__ void focal_main(const float* __restrict__ cls,
                           const float* __restrict__ reg,
                           const float* __restrict__ anc,
                           const float* __restrict__ ann,
                           float* __restrict__ ws) {
    const int b     = blockIdx.y;
    const int chunk = blockIdx.x;
    const int tid   = threadIdx.x;

    __shared__ float s_ann[NANN * 5];
    __shared__ float s_m[CHUNK];               // 0 = ignore, 1 = count (neg or pos)
    __shared__ float s_red[(BLOCK / 64) * 3];

    if (tid < NANN * 5) s_ann[tid] = ann[b * NANN * 5 + tid];
    __syncthreads();

    const int k0 = chunk * CHUNK;
    const int k  = k0 + tid;

    float reg_acc  = 0.0f;
    float np_acc   = 0.0f;
    float cls_corr = 0.0f;   // positive-anchor class-term swap (exact units)
    float m        = 0.0f;

    if (k < K_) {
        float4 a = *(const float4*)(anc + (size_t)k * 4);
        float aw = a.z - a.x, ah = a.w - a.y;
        float area_a = aw * ah;

        float best = -2.0f;
        int bestj = 0;
        for (int j = 0; j < NANN; ++j) {
            float bx1 = s_ann[j * 5 + 0], by1 = s_ann[j * 5 + 1];
            float bx2 = s_ann[j * 5 + 2], by2 = s_ann[j * 5 + 3];
            float lbl = s_ann[j * 5 + 4];
            float area_b = (bx2 - bx1) * (by2 - by1);
            float iw = fmaxf(fminf(a.z, bx2) - fmaxf(a.x, bx1), 0.0f);
            float ih = fmaxf(fminf(a.w, by2) - fmaxf(a.y, by1), 0.0f);
            float inter = iw * ih;
            float uni = fmaxf(area_a + area_b - inter, 1e-8f);
            float iou = inter / uni;
            if (lbl < 0.0f) iou = -1.0f;            // invalid annotation mask
            if (iou > best) { best = iou; bestj = j; }  // first-max = jnp.argmax
        }

        if (best >= 0.5f) {                         // positive anchor
            m = 1.0f;
            np_acc = 1.0f;
            int c = (int)s_ann[bestj * 5 + 4];
            // correction: sweep will apply the NEG formula at class c; swap it
            // for the POS formula. p in (0.01,0.99) -> clamp is a no-op.
            float p  = cls[((size_t)b * K_ + k) * C_ + c];
            float pm = 1.0f - p;
            float pos_term = -0.25f * fast_sqrt(pm) * (fast_log2(p)  * LN2);
            float neg_term = -0.75f * fast_sqrt(p)  * (fast_log2(pm) * LN2);
            cls_corr = pos_term - neg_term;

            // regression smooth-L1
            float gx1 = s_ann[bestj * 5 + 0], gy1 = s_ann[bestj * 5 + 1];
            float gx2 = s_ann[bestj * 5 + 2], gy2 = s_ann[bestj * 5 + 3];
            float gw = fmaxf(gx2 - gx1, 1.0f);
            float gh = fmaxf(gy2 - gy1, 1.0f);
            float gcx = gx1 + 0.5f * gw, gcy = gy1 + 0.5f * gh;
            float acx = a.x + 0.5f * aw, acy = a.y + 0.5f * ah;
            float4 r = *(const float4*)(reg + ((size_t)b * K_ + k) * 4);
            float t0 = ((gcx - acx) / aw) * 10.0f;
            float t1 = ((gcy - acy) / ah) * 10.0f;
            float t2 = (fast_log2(gw / aw) * LN2) * 5.0f;
            float t3 = (fast_log2(gh / ah) * LN2) * 5.0f;
            float d, s;
            d = fabsf(t0 - r.x); s = (d <= 1.0f/9.0f) ? 4.5f*d*d : d - 0.5f/9.0f; reg_acc += s;
            d = fabsf(t1 - r.y); s = (d <= 1.0f/9.0f) ? 4.5f*d*d : d - 0.5f/9.0f; reg_acc += s;
            d = fabsf(t2 - r.z); s = (d <= 1.0f/9.0f) ? 4.5f*d*d : d - 0.5f/9.0f; reg_acc += s;
            d = fabsf(t3 - r.w); s = (d <= 1.0f/9.0f) ? 4.5f*d*d : d - 0.5f/9.0f; reg_acc += s;
        } else if (best < 0.4f) {
            m = 1.0f;                               // negative anchor
        } // else ignore: m = 0
    }
    s_m[tid] = m;
    __syncthreads();

    // ---- classification sweep: acc = sum m * sqrt(p) * log2(1-p) ----
    const int na  = min(CHUNK, K_ - k0);
    const int nf4 = na * (C_ / 4);
    const float4* __restrict__ cp =
        (const float4*)(cls + ((size_t)b * K_ + (size_t)k0) * C_);

    float a0 = 0.0f, a1 = 0.0f, a2 = 0.0f, a3 = 0.0f;

    if (na == CHUNK) {
        const int NIT = CHUNK * (C_ / 4) / BLOCK;   // 20, compile-time
#pragma unroll 5
        for (int it = 0; it < NIT; ++it) {
            int idx = tid + it * BLOCK;
            int a_l = (idx * 3277) >> 16;           // idx/20, exact for idx<5120
            float mm = s_m[a_l];
            float4 x = cp[idx];
            a0 = fmaf(mm, fast_sqrt(x.x) * fast_log2(1.0f - x.x), a0);
            a1 = fmaf(mm, fast_sqrt(x.y) * fast_log2(1.0f - x.y), a1);
            a2 = fmaf(mm, fast_sqrt(x.z) * fast_log2(1.0f - x.z), a2);
            a3 = fmaf(mm, fast_sqrt(x.w) * fast_log2(1.0f - x.w), a3);
        }
    } else {
        for (int idx = tid; idx < nf4; idx += BLOCK) {
            int a_l = (idx * 3277) >> 16;
            float mm = s_m[a_l];
            float4 x = cp[idx];
            a0 = fmaf(mm, fast_sqrt(x.x) * fast_log2(1.0f - x.x), a0);
            a1 = fmaf(mm, fast_sqrt(x.y) * fast_log2(1.0f - x.y), a1);
            a2 = fmaf(mm, fast_sqrt(x.z) * fast_log2(1.0f - x.z), a2);
            a3 = fmaf(mm, fast_sqrt(x.w) * fast_log2(1.0f - x.w), a3);
        }
    }

    float cls_acc = ((a0 + a1) + (a2 + a3)) * (-0.75f * LN2) + cls_corr;

    // ---- block reduction of (cls_acc, reg_acc, np_acc) ----
    float v0 = cls_acc, v1 = reg_acc, v2 = np_acc;
    for (int off = 32; off > 0; off >>= 1) {
        v0 += __shfl_down(v0, off, 64);
        v1 += __shfl_down(v1, off, 64);
        v2 += __shfl_down(v2, off, 64);
    }
    int wave = tid >> 6, lane = tid & 63;
    if (lane == 0) {
        s_red[wave * 3 + 0] = v0;
        s_red[wave * 3 + 1] = v1;
        s_red[wave * 3 + 2] = v2;
    }
    __syncthreads();
    if (tid == 0) {
        float c = 0.0f, rg = 0.0f, np = 0.0f;
        for (int w = 0; w < BLOCK / 64; ++w) {
            c  += s_red[w * 3 + 0];
            rg += s_red[w * 3 + 1];
            np += s_red[w * 3 + 2];
        }
        atomicAdd(&ws[b * 3 + 0], c);
        atomicAdd(&ws[b * 3 + 1], rg);
        atomicAdd(&ws[b * 3 + 2], np);
    }
}

__global__ void finalize_kernel(const float* __restrict__ ws, float* __restrict__ out) {
    if (threadIdx.x == 0) {
        float cs = 0.0f, rs = 0.0f;
        for (int b = 0; b < B_; ++b) {
            float c  = ws[b * 3 + 0];
            float r  = ws[b * 3 + 1];
            float np = ws[b * 3 + 2];
            cs += c / fmaxf(np, 1.0f);
            rs += (np > 0.0f) ? r / fmaxf(np * 4.0f, 1.0f) : 0.0f;
        }
        out[0] = cs / (float)B_;
        out[1] = rs / (float)B_;
    }
}

extern "C" void kernel_launch(void* const* d_in, const int* in_sizes, int n_in,
                              void* d_out, int out_size, void* d_ws, size_t ws_size,
                              hipStream_t stream) {
    const float* cls = (const float*)d_in[0];   // [B,K,C]
    const float* reg = (const float*)d_in[1];   // [B,K,4]
    const float* anc = (const float*)d_in[2];   // [1,K,4]
    const float* ann = (const float*)d_in[3];   // [B,NANN,5]
    float* out = (float*)d_out;                  // [2]
    float* ws  = (float*)d_ws;                   // 24 floats: per-batch {cls,reg,npos}

    zero_ws_kernel<<<1, 64, 0, stream>>>(ws);

    dim3 grid((K_ + CHUNK - 1) / CHUNK, B_);
    focal_main<<<grid, BLOCK, 0, stream>>>(cls, reg, anc, ann, ws);

    finalize_kernel<<<1, 64, 0, stream>>>(ws, out);
}